// Round 14
// baseline (114.753 us; speedup 1.0000x reference)
//
#include <hip/hip_runtime.h>

#define N 8192
#define D 256

typedef short short8 __attribute__((ext_vector_type(8)));
typedef float f32x4 __attribute__((ext_vector_type(4)));

__device__ __forceinline__ unsigned short f2bf(float f) {
    unsigned int u = __float_as_uint(f);
    u += 0x7fffu + ((u >> 16) & 1u);   // RNE
    return (unsigned short)(u >> 16);
}
__device__ __forceinline__ float bf2f(unsigned short h) {
    return __uint_as_float(((unsigned int)h) << 16);
}

// async global->LDS, 16B per lane; dst is wave-uniform base + lane*16
#define GLDS16(g, l) __builtin_amdgcn_global_load_lds(                      \
    (const __attribute__((address_space(1))) void*)(g),                     \
    (__attribute__((address_space(3))) void*)(l), 16, 0, 0)

// Kernel 0: fp32 -> bf16 conversion into FRAGMENT-MAJOR layout xb2 (R13):
// 16B chunk ((row>>4)*8 + kk)*64 + lane holds
// X[(row>>4)*16 + (lane&15)][kk*32 + (lane>>4)*8 .. +8) as bf16.
// Any 64-col MFMA tile is a contiguous 32 KB block. Also row squared norms
// + zero S/L accumulators.
__global__ __launch_bounds__(256) void k_cvt(const float* __restrict__ x,
                                             unsigned short* __restrict__ xb2,
                                             float* __restrict__ sq,
                                             float* __restrict__ Sarr,
                                             float* __restrict__ Larr) {
    const int wv = threadIdx.x >> 6, lane = threadIdx.x & 63;
    const int c = lane & 15, q8 = lane >> 4;
    const int grp = blockIdx.x * 4 + wv;      // 16-row group
    const int row = grp * 16 + c;

    float ssum = 0.0f;
#pragma unroll
    for (int kk = 0; kk < 8; ++kk) {
        const float4* gp = (const float4*)(x + (size_t)row * D + kk * 32 + q8 * 8);
        float4 v0 = gp[0], v1 = gp[1];
        unsigned short h[8];
        h[0] = f2bf(v0.x); h[1] = f2bf(v0.y); h[2] = f2bf(v0.z); h[3] = f2bf(v0.w);
        h[4] = f2bf(v1.x); h[5] = f2bf(v1.y); h[6] = f2bf(v1.z); h[7] = f2bf(v1.w);
        short8 p;
#pragma unroll
        for (int i = 0; i < 8; ++i) {
            float f = bf2f(h[i]);
            ssum = fmaf(f, f, ssum);
            p[i] = (short)h[i];
        }
        ((short8*)xb2)[(grp * 8 + kk) * 64 + lane] = p;
    }
    ssum += __shfl_xor(ssum, 16, 64);
    ssum += __shfl_xor(ssum, 32, 64);
    if (q8 == 0) {
        sq[row] = ssum;
        Sarr[row] = 0.0f;
        Larr[row] = 0.0f;
    }
}

// Kernel 1: SYMMETRIC Gram on the R13 pipeline. One 256x256 upper-triangular
// tile (i<=j) per block; 528 blocks (triangular decode; consecutive blocks
// share i, j contiguous -> L2 locality, fixing R5). 64 rows/wave (A in 128
// VGPRs, fragment-major coalesced loads), 4 x 64-col subtiles through the
// 2x32 KB ping-pong fragment-sequential LDS (0 conflicts). Screened exp2
// epilogue: unflagged subtiles contribute exactly 0 (fp32 underflow,
// identical to the reference), so row AND col (transpose) commits happen
// only in the rare flagged branch; col commits skipped when i==j (the
// diagonal tile's full square is covered by its row commits).
// Additive-pipe model: MFMA 8.5 + LDS 5.3 + VALU ~5 + stage ~1.5 => ~24 us.
__global__ __launch_bounds__(256, 2) void k_gram(const unsigned short* __restrict__ xb2,
                                                 const float* __restrict__ sq,
                                                 const float* __restrict__ temp,
                                                 float* __restrict__ Sarr,
                                                 float* __restrict__ Larr) {
    __shared__ unsigned short Bs[2][64 * D];   // 2 x 32 KB, fragment-sequential

    const int tid = threadIdx.x;
    const int wv = tid >> 6, lane = tid & 63;
    const int q8 = lane >> 4, c = lane & 15;

    // triangular decode: block b -> (i, j), j >= i; C(i) = i*(65-i)/2
    const int b = blockIdx.x;
    int i = (int)((65.0f - sqrtf(4225.0f - 8.0f * (float)b)) * 0.5f);
    while ((i * (65 - i)) / 2 > b) --i;
    while (((i + 1) * (64 - i)) / 2 <= b) ++i;
    const int j = i + (b - (i * (65 - i)) / 2);
    const int rowbase = i * 256;
    const int colbase = j * 256;

    const float T = temp[0];
    const float LOG2E = 1.44269504f;
    const float s2 = -LOG2E / (2.0f * T * T);   // log2-scaled; t2 = c2*g + ar + bc
    const float c2 = -2.0f * s2;
    const float LN2 = 0.69314718f;

    // A fragments: wave wv owns rows rowbase + wv*64 .. +63 (coalesced)
    short8 av[4][8];
#pragma unroll
    for (int tr = 0; tr < 4; ++tr) {
        const int grp = (rowbase >> 4) + wv * 4 + tr;
#pragma unroll
        for (int kk = 0; kk < 8; ++kk)
            av[tr][kk] = ((const short8*)xb2)[(grp * 8 + kk) * 64 + lane];
    }
    float ar[16];   // sq[row] * s2 (negative)
#pragma unroll
    for (int tr = 0; tr < 4; ++tr)
#pragma unroll
        for (int r = 0; r < 4; ++r)
            ar[tr * 4 + r] = sq[rowbase + wv * 64 + tr * 16 + q8 * 4 + r] * s2;
    float armax = ar[0];
#pragma unroll
    for (int k = 1; k < 16; ++k) armax = fmaxf(armax, ar[k]);

    float Sr[16], Mr[16];
#pragma unroll
    for (int k = 0; k < 16; ++k) { Sr[k] = 0.f; Mr[k] = 0.f; }

    // staging: 64-col subtile = contiguous 32 KB of xb2 = 32 segs of 1 KB;
    // wave wv stages segs wv*8 .. +7; src = chunkbase + s*512 + lane*8
#pragma unroll
    for (int g2 = 0; g2 < 8; ++g2) {
        int s = wv * 8 + g2;
        const unsigned short* src =
            xb2 + (size_t)(colbase >> 4) * 4096 + s * 512 + lane * 8;
        GLDS16(src, &Bs[0][0] + s * 512);
    }

    for (int ht = 0; ht < 4; ++ht) {
        const int tilebase = colbase + ht * 64;
        const int cur = ht & 1;

        __syncthreads();   // drains stage of ht; fences buffer reuse (ht-2)

        if (ht < 3) {
            const size_t nchunk = (size_t)((tilebase + 64) >> 4) * 4096;
#pragma unroll
            for (int g2 = 0; g2 < 8; ++g2) {
                int s = wv * 8 + g2;
                const unsigned short* src = xb2 + nchunk + s * 512 + lane * 8;
                GLDS16(src, &Bs[cur ^ 1][0] + s * 512);
            }
        }

#pragma unroll
        for (int tc = 0; tc < 4; ++tc) {
            const float bc = sq[tilebase + tc * 16 + c] * s2;
            const unsigned short* bb = &Bs[cur][0] + tc * 8 * 512 + lane * 8;

            short8 bva[4];
#pragma unroll
            for (int kk = 0; kk < 4; ++kk)
                bva[kk] = *(const short8*)(bb + kk * 512);

            f32x4 acc[4];
#pragma unroll
            for (int tr = 0; tr < 4; ++tr)
#pragma unroll
                for (int r = 0; r < 4; ++r) acc[tr][r] = 0.0f;

#pragma unroll
            for (int kk = 0; kk < 4; ++kk)
#pragma unroll
                for (int tr = 0; tr < 4; ++tr)
                    acc[tr] = __builtin_amdgcn_mfma_f32_16x16x32_bf16(
                        av[tr][kk], bva[kk], acc[tr], 0, 0, 0);

            short8 bvb[4];
#pragma unroll
            for (int kk = 0; kk < 4; ++kk)
                bvb[kk] = *(const short8*)(bb + (kk + 4) * 512);

#pragma unroll
            for (int kk = 0; kk < 4; ++kk)
#pragma unroll
                for (int tr = 0; tr < 4; ++tr)
                    acc[tr] = __builtin_amdgcn_mfma_f32_16x16x32_bf16(
                        av[tr][kk + 4], bvb[kk], acc[tr], 0, 0, 0);

            // screen: conservative upper bound on t2 over this lane's 16 elems
            float gmax = acc[0][0];
#pragma unroll
            for (int tr = 0; tr < 4; ++tr)
#pragma unroll
                for (int r = 0; r < 4; ++r) gmax = fmaxf(gmax, acc[tr][r]);
            const float bound = fmaf(gmax, c2, armax + bc);

            if (__any(bound >= -115.0f)) {
                // exact slow path (diagonal-touching subtiles, ~1%)
                float colS = 0.0f, colM = 0.0f;
#pragma unroll
                for (int tr = 0; tr < 4; ++tr)
#pragma unroll
                    for (int r = 0; r < 4; ++r) {
                        float g = acc[tr][r];
                        float t2 = fminf(fmaf(g, c2, ar[tr * 4 + r] + bc), 0.0f);
                        float e = __builtin_amdgcn_exp2f(t2);
                        Sr[tr * 4 + r] += e;
                        Mr[tr * 4 + r] = fmaf(e, t2, Mr[tr * 4 + r]);
                        colS += e;
                        colM = fmaf(e, t2, colM);
                    }
                // transpose (col) contribution — off-diagonal tiles only
                if (i != j) {
                    colS += __shfl_xor(colS, 16, 64);
                    colM += __shfl_xor(colM, 16, 64);
                    colS += __shfl_xor(colS, 32, 64);
                    colM += __shfl_xor(colM, 32, 64);
                    if (q8 == 0) {
                        atomicAdd(&Sarr[tilebase + tc * 16 + c], colS);
                        atomicAdd(&Larr[tilebase + tc * 16 + c], colM * LN2);
                    }
                }
            }
            // else: all values underflow fp32 -> contribute exactly 0
        }
    }

    // row-sum commit: reduce across the 16 col-lanes (lane bits 0..3)
#pragma unroll
    for (int m = 1; m <= 8; m <<= 1)
#pragma unroll
        for (int k = 0; k < 16; ++k) {
            Sr[k] += __shfl_xor(Sr[k], m, 64);
            Mr[k] += __shfl_xor(Mr[k], m, 64);
        }
    if (c == 0) {
#pragma unroll
        for (int k = 0; k < 16; ++k) {
            int row = rowbase + wv * 64 + (k >> 2) * 16 + q8 * 4 + (k & 3);
            atomicAdd(&Sarr[row], Sr[k]);
            atomicAdd(&Larr[row], Mr[k] * LN2);
        }
    }
}

// Kernel 2 (merged ctrl+scale): per row H = log(S) - L/S,
// cs = sigmoid(-(H - target)/T); write scaled features + control signal.
__global__ __launch_bounds__(256) void k_finish(const float* __restrict__ x,
                                                const float* __restrict__ Sarr,
                                                const float* __restrict__ Larr,
                                                const float* __restrict__ target,
                                                const float* __restrict__ temp,
                                                float* __restrict__ out) {
    const int gid = blockIdx.x * 256 + threadIdx.x;  // float4 index
    const int row = gid >> 6;                        // 64 float4 per row
    float S = Sarr[row], L = Larr[row];
    float H = __logf(S) - L / S;
    float z = (H - target[0]) / temp[0];
    float cs = 1.0f / (1.0f + __expf(z));
    float4 v = ((const float4*)x)[gid];
    float4 o;
    o.x = v.x * cs; o.y = v.y * cs; o.z = v.z * cs; o.w = v.w * cs;
    ((float4*)out)[gid] = o;
    if ((gid & 63) == 0) out[(size_t)N * D + row] = cs;  // control_signal section
}

extern "C" void kernel_launch(void* const* d_in, const int* in_sizes, int n_in,
                              void* d_out, int out_size, void* d_ws, size_t ws_size,
                              hipStream_t stream) {
    const float* x = (const float*)d_in[0];       // features [4,2048,256]
    const float* target = (const float*)d_in[7];  // target_entropy [1]
    const float* temp = (const float*)d_in[8];    // temperature [1]
    float* out = (float*)d_out;

    float* wsf = (float*)d_ws;
    float* sq = wsf;
    float* Sarr = wsf + N;
    float* Larr = wsf + 2 * N;

    // fragment-major bf16 copy of X: in ws if it fits, else park in d_out's
    // first 4 MB (k_finish only writes d_out after k_gram has consumed xb2)
    const size_t need = 3 * (size_t)N * sizeof(float) + (size_t)N * D * sizeof(unsigned short);
    unsigned short* xb2 = (ws_size >= need) ? (unsigned short*)(wsf + 3 * N)
                                            : (unsigned short*)d_out;

    k_cvt<<<N / 64, 256, 0, stream>>>(x, xb2, sq, Sarr, Larr);
    k_gram<<<528, 256, 0, stream>>>(xb2, sq, temp, Sarr, Larr);   // 32*33/2 tiles
    k_finish<<<(N * (D / 4)) / 256, 256, 0, stream>>>(x, Sarr, Larr, target, temp, out);
}